// Round 5
// baseline (419.387 us; speedup 1.0000x reference)
//
#include <hip/hip_runtime.h>
#include <hip/hip_bf16.h>

#define OUT1 16777216    // 4*64*256*256
#define BIG  33554432    // 4*128*256*256

typedef _Float16 half8 __attribute__((ext_vector_type(8)));
typedef float    floatx4 __attribute__((ext_vector_type(4)));

struct __align__(8) h4s { _Float16 x, y, z, w; };
__device__ inline void store4h(_Float16* p, float4 v){
    h4s t; t.x = (_Float16)v.x; t.y = (_Float16)v.y; t.z = (_Float16)v.z; t.w = (_Float16)v.w;
    *(h4s*)p = t;
}

// ---------------- K1: bilinear upsample 64x64 -> 256x256 (align_corners) + clip ----------------
__global__ __launch_bounds__(256) void k_prior(const float* __restrict__ prior, float* __restrict__ pu){
    int i = blockIdx.x*256 + threadIdx.x;       // 0..262143
    int b = i >> 16;
    int rem = i & 65535;
    int yy = rem >> 8, xx = rem & 255;
    const float scale = 63.0f/255.0f;
    float sy = yy*scale, sx = xx*scale;
    int y0 = min((int)floorf(sy), 63), x0 = min((int)floorf(sx), 63);
    int y1 = min(y0+1, 63), x1 = min(x0+1, 63);
    float wy = sy - (float)y0, wx = sx - (float)x0;
    const float* pb = prior + (b<<12);
    float v00 = pb[(y0<<6)+x0], v01 = pb[(y0<<6)+x1];
    float v10 = pb[(y1<<6)+x0], v11 = pb[(y1<<6)+x1];
    float r0 = v00*(1.f-wy) + v10*wy;
    float r1 = v01*(1.f-wy) + v11*wy;
    float v  = r0*(1.f-wx) + r1*wx;
    pu[i] = fminf(fmaxf(v, -1.f), 1.f);
}

// ---------------- K0: fold weights (f16): Wch(384x64), biases, -exp(A), Wof(64x128) ----------
__global__ __launch_bounds__(256) void k_comb(const float* __restrict__ W_in, const float* __restrict__ b_in,
        const float* __restrict__ W_delta, const float* __restrict__ b_delta,
        const float* __restrict__ W_B, const float* __restrict__ b_B,
        const float* __restrict__ A_param, const float* __restrict__ W_out,
        _Float16* __restrict__ Wch, float* __restrict__ bcv, float* __restrict__ negA,
        _Float16* __restrict__ Wof){
    int i = blockIdx.x*256 + threadIdx.x;
    if (i < 24576){
        int r = i >> 6, c = i & 63;
        float v;
        if (r < 128) v = W_in[i];
        else if (r < 256){
            int rr = r-128; float s = 0.f;
            for (int k=0;k<128;k++) s = fmaf(W_delta[(rr<<7)+k], W_in[(k<<6)+c], s);
            v = s;
        } else {
            int rr = r-256; float s = 0.f;
            for (int k=0;k<128;k++) s = fmaf(W_B[(rr<<7)+k], W_in[(k<<6)+c], s);
            v = s;
        }
        Wch[i] = (_Float16)v;
    } else if (i < 24960){
        int r = i - 24576; float v;
        if (r < 128) v = b_in[r];
        else if (r < 256){
            int rr=r-128; float s = b_delta[rr];
            for (int k=0;k<128;k++) s = fmaf(W_delta[(rr<<7)+k], b_in[k], s);
            v = s;
        } else {
            int rr=r-256; float s = b_B[rr];
            for (int k=0;k<128;k++) s = fmaf(W_B[(rr<<7)+k], b_in[k], s);
            v = s;
        }
        bcv[r] = v;
    } else if (i < 25088){
        negA[i-24960] = -expf(A_param[i-24960]);
    } else if (i < 33280){
        Wof[i-25088] = (_Float16)W_out[i-25088];   // [o][k] row-major, 64x128
    }
}

// ---------------- K2: MFMA projection: [384 x 64] @ [64 x 256px] per block -> f16 Ab,Uu --------
// A-frag: A[m=lane&15][k=quad*8+j]; C/D: col=lane&15 (=pixel), row=quad*4+reg (=channel).
// __launch_bounds__(256,2): VGPR cap 256 — acc(48)+frags(24)+staging must NOT spill (R4: 72 VGPR = spill hell)
__global__ __launch_bounds__(256, 2) void k_proj_mfma(const float* __restrict__ x, const float* __restrict__ pu,
        const _Float16* __restrict__ Wch, const float* __restrict__ bcv, const float* __restrict__ negA,
        const float* __restrict__ lam_p, const float* __restrict__ alp_p,
        _Float16* __restrict__ Ab, _Float16* __restrict__ Uu){
    __shared__ _Float16 Xs[256][72];   // [pixel][k] f16, pad 64->72
    __shared__ _Float16 Ws[48][72];    // [m-row][k]  f16

    const int t    = threadIdx.x;
    const int lane = t & 63;
    const int wave = t >> 6;
    const int col  = lane & 15;
    const int quad = lane >> 4;
    const int c0   = blockIdx.y << 4;          // 0,16,...,112

    const int b     = blockIdx.x >> 8;
    const int p16_0 = (blockIdx.x & 255) << 8;

    const float* xcol = x + ((size_t)b<<22) + p16_0 + t;
    #pragma unroll
    for (int k0 = 0; k0 < 64; k0 += 8){
        half8 h;
        #pragma unroll
        for (int j = 0; j < 8; j++) h[j] = (_Float16)xcol[(size_t)(k0+j)<<16];
        *(half8*)&Xs[t][k0] = h;
    }
    if (t < 48){
        int g = t >> 4;
        int row = (g<<7) + c0 + (t & 15);
        const half8* src = (const half8*)(Wch + row*64);
        #pragma unroll
        for (int j = 0; j < 8; j++) ((half8*)&Ws[t][0])[j] = src[j];
    }
    __syncthreads();

    half8 aW[3][2];
    #pragma unroll
    for (int mt = 0; mt < 3; mt++)
        #pragma unroll
        for (int kh = 0; kh < 2; kh++)
            aW[mt][kh] = *(const half8*)&Ws[mt*16 + col][kh*32 + quad*8];

    const int wn0 = wave << 6;
    floatx4 acc[3][4];
    #pragma unroll
    for (int mt = 0; mt < 3; mt++)
        #pragma unroll
        for (int nt = 0; nt < 4; nt++)
            acc[mt][nt] = (floatx4){0.f, 0.f, 0.f, 0.f};

    #pragma unroll
    for (int nt = 0; nt < 4; nt++){
        half8 b0 = *(const half8*)&Xs[wn0 + nt*16 + col][ 0 + quad*8];
        half8 b1 = *(const half8*)&Xs[wn0 + nt*16 + col][32 + quad*8];
        #pragma unroll
        for (int mt = 0; mt < 3; mt++){
            acc[mt][nt] = __builtin_amdgcn_mfma_f32_16x16x32_f16(aW[mt][0], b0, acc[mt][nt], 0, 0, 0);
            acc[mt][nt] = __builtin_amdgcn_mfma_f32_16x16x32_f16(aW[mt][1], b1, acc[mt][nt], 0, 0, 0);
        }
    }

    const float lamv = lam_p[0], alpv = alp_p[0];
    #pragma unroll
    for (int nt = 0; nt < 4; nt++){
        int p_local = wn0 + nt*16 + col;
        float puv = pu[(blockIdx.x<<8) + p_local];
        float lpu = lamv * puv;
        float apu = fmaf(alpv, puv, 1.f);
        size_t pb = ((size_t)b<<23) + p16_0 + p_local;
        #pragma unroll
        for (int r = 0; r < 4; r++){
            int c = c0 + quad*4 + r;           // channel in [0,128)
            float sI = acc[0][nt][r] + bcv[c];
            float sD = acc[1][nt][r] + bcv[128+c];
            float sB = acc[2][nt][r] + bcv[256+c];
            float dpre  = sD + lpu;
            float delta = fmaxf(dpre, 0.f) + log1pf(expf(-fabsf(dpre)));
            float ab    = expf(negA[c]*delta);
            float u     = delta * sB * apu * sI;
            size_t o = pb + ((size_t)c<<16);
            Ab[o] = (_Float16)ab;
            Uu[o] = (_Float16)u;
        }
    }
}

// ---------------- K3: scan along W — one wave per row, shuffle linear-recurrence scan ----------
__global__ __launch_bounds__(256) void k_scan_w(const _Float16* __restrict__ Ab, const _Float16* __restrict__ Uu,
                                                _Float16* __restrict__ Sw){
    int r    = (blockIdx.x<<2) + (threadIdx.x>>6);   // row id over (b,c,h): 0..131071
    int lane = threadIdx.x & 63;
    size_t base = ((size_t)r<<8) + (lane<<2);
    h4s a4 = *(const h4s*)(Ab+base);
    h4s u4 = *(const h4s*)(Uu+base);
    float ax=(float)a4.x, ay=(float)a4.y, az=(float)a4.z, aw=(float)a4.w;
    float ux=(float)u4.x, uy=(float)u4.y, uz=(float)u4.z, uw=(float)u4.w;
    float A = ax, U = ux;
    U = fmaf(ay, U, uy); A *= ay;
    U = fmaf(az, U, uz); A *= az;
    U = fmaf(aw, U, uw); A *= aw;
    #pragma unroll
    for (int off=1; off<64; off<<=1){
        float Apv = __shfl_up(A, off, 64);
        float Upv = __shfl_up(U, off, 64);
        if (lane >= off){ U = fmaf(A, Upv, U); A *= Apv; }
    }
    float h = __shfl_up(U, 1, 64);     // exclusive prefix
    if (lane == 0) h = 0.f;
    float4 o;
    h = fmaf(ax, h, ux); o.x = h;
    h = fmaf(ay, h, uy); o.y = h;
    h = fmaf(az, h, uz); o.z = h;
    h = fmaf(aw, h, uw); o.w = h;
    store4h(Sw+base, o);
}

// ---------------- K4: scan along H (thread per column) + add scanW -> Sh f16 ----------
__global__ __launch_bounds__(256) void k_scan_h(const _Float16* __restrict__ AbH, const _Float16* __restrict__ UuH,
                                                const _Float16* __restrict__ Sw, _Float16* __restrict__ Sh){
    int t   = blockIdx.x*256 + threadIdx.x;    // 0..131071
    int col = t >> 8;                          // b*128 + c
    int w   = t & 255;
    size_t base = ((size_t)col<<16) + w;
    float h = 0.f;
    #pragma unroll 4
    for (int hh=0; hh<256; hh++){
        size_t idx = base + ((size_t)hh<<8);
        float a = (float)AbH[idx];
        float u = (float)UuH[idx];
        float s = (float)Sw[idx];
        h = fmaf(a, h, u);
        Sh[idx] = (_Float16)(h + s);           // scanned = scanH + scanW
    }
}

// ---------------- K5: MFMA output conv (128->64) + residual ----------------
// A = Wof[64][128] f16; B = Sh[k=128][n=px] f16; D: col=pixel, quad*4+r = out-ch within tile.
__global__ __launch_bounds__(256, 2) void k_out_mfma(const float* __restrict__ x, const _Float16* __restrict__ Sh,
        const _Float16* __restrict__ Wof, const float* __restrict__ bout, const float* __restrict__ gam_p,
        float* __restrict__ out){
    const int t    = threadIdx.x;
    const int lane = t & 63;
    const int wave = t >> 6;
    const int col  = lane & 15;
    const int quad = lane >> 4;
    const int b    = blockIdx.x >> 8;
    const int p0   = (blockIdx.x & 255) << 8;
    const int wn0  = wave << 6;

    const _Float16* shb = Sh + ((size_t)b<<23) + p0;

    floatx4 acc[4][4];
    #pragma unroll
    for (int mt = 0; mt < 4; mt++)
        #pragma unroll
        for (int nt = 0; nt < 4; nt++)
            acc[mt][nt] = (floatx4){0.f,0.f,0.f,0.f};

    #pragma unroll
    for (int kc = 0; kc < 4; kc++){
        half8 bf[4];
        #pragma unroll
        for (int nt = 0; nt < 4; nt++){
            int px = wn0 + nt*16 + col;
            #pragma unroll
            for (int j = 0; j < 8; j++)
                bf[nt][j] = shb[((size_t)(kc*32 + quad*8 + j)<<16) + px];
        }
        half8 af[4];
        #pragma unroll
        for (int mt = 0; mt < 4; mt++)
            af[mt] = *(const half8*)(Wof + (mt*16 + col)*128 + kc*32 + quad*8);
        #pragma unroll
        for (int mt = 0; mt < 4; mt++)
            #pragma unroll
            for (int nt = 0; nt < 4; nt++)
                acc[mt][nt] = __builtin_amdgcn_mfma_f32_16x16x32_f16(af[mt], bf[nt], acc[mt][nt], 0, 0, 0);
    }

    const float gv = gam_p[0];
    #pragma unroll
    for (int mt = 0; mt < 4; mt++){
        #pragma unroll
        for (int nt = 0; nt < 4; nt++){
            int px = wn0 + nt*16 + col;
            #pragma unroll
            for (int r = 0; r < 4; r++){
                int o = mt*16 + quad*4 + r;
                size_t idx = (((size_t)(b*64 + o))<<16) + p0 + px;
                out[idx] = fmaf(gv, acc[mt][nt][r] + bout[o], x[idx]);
            }
        }
    }
}

extern "C" void kernel_launch(void* const* d_in, const int* in_sizes, int n_in,
                              void* d_out, int out_size, void* d_ws, size_t ws_size,
                              hipStream_t stream){
    const float* x       = (const float*)d_in[0];
    const float* prior   = (const float*)d_in[1];
    const float* W_in    = (const float*)d_in[2];
    const float* b_in    = (const float*)d_in[3];
    const float* W_out   = (const float*)d_in[4];
    const float* b_out   = (const float*)d_in[5];
    const float* W_delta = (const float*)d_in[6];
    const float* b_delta = (const float*)d_in[7];
    const float* W_B     = (const float*)d_in[8];
    const float* b_B     = (const float*)d_in[9];
    const float* A_param = (const float*)d_in[10];
    const float* lam     = (const float*)d_in[11];
    const float* alp     = (const float*)d_in[12];
    const float* gam     = (const float*)d_in[13];

    float* out = (float*)d_out;
    float* pu  = out + OUT1;                   // prior_up = output 1

    float* ws        = (float*)d_ws;
    _Float16* Wch    = (_Float16*)ws;          // 24576 f16 -> float-offset [0,12288)
    float* bcv       = ws + 12288;             // 384
    float* negA      = ws + 12672;             // 128
    _Float16* Wof    = (_Float16*)(ws + 12800);// 8192 f16 -> [12800,16896)
    _Float16* AbH    = (_Float16*)(ws + 32768);// BIG f16
    _Float16* UuH    = AbH + BIG;              // BIG f16
    _Float16* Sh     = UuH + BIG;              // BIG f16   (total 201.5 MB)
    _Float16* Sw     = (_Float16*)out;         // f16 W-scan scratch in d_out[0:OUT1), 67 MB

    hipLaunchKernelGGL(k_prior,  dim3(1024),  dim3(256), 0, stream, prior, pu);
    hipLaunchKernelGGL(k_comb,   dim3(130),   dim3(256), 0, stream, W_in, b_in, W_delta, b_delta,
                       W_B, b_B, A_param, W_out, Wch, bcv, negA, Wof);
    hipLaunchKernelGGL(k_proj_mfma, dim3(1024, 8), dim3(256), 0, stream,
                       x, pu, Wch, bcv, negA, lam, alp, AbH, UuH);
    hipLaunchKernelGGL(k_scan_w, dim3(32768), dim3(256), 0, stream, AbH, UuH, Sw);
    hipLaunchKernelGGL(k_scan_h, dim3(512),   dim3(256), 0, stream, AbH, UuH, Sw, Sh);
    hipLaunchKernelGGL(k_out_mfma, dim3(1024), dim3(256), 0, stream, x, Sh, Wof, b_out, gam, out);
}

// Round 7
// 323.534 us; speedup vs baseline: 1.2963x; 1.2963x over previous
//
#include <hip/hip_runtime.h>
#include <hip/hip_bf16.h>

#define OUT1 16777216    // 4*64*256*256
#define BIG  33554432    // 4*128*256*256

typedef _Float16 half8 __attribute__((ext_vector_type(8)));
typedef float    floatx4 __attribute__((ext_vector_type(4)));

struct __align__(8) h4s { _Float16 x, y, z, w; };
__device__ inline void store4h(_Float16* p, float4 v){
    h4s t; t.x = (_Float16)v.x; t.y = (_Float16)v.y; t.z = (_Float16)v.z; t.w = (_Float16)v.w;
    *(h4s*)p = t;
}

// ---------------- K1: bilinear upsample 64x64 -> 256x256 (align_corners) + clip ----------------
__global__ __launch_bounds__(256) void k_prior(const float* __restrict__ prior, float* __restrict__ pu){
    int i = blockIdx.x*256 + threadIdx.x;       // 0..262143
    int b = i >> 16;
    int rem = i & 65535;
    int yy = rem >> 8, xx = rem & 255;
    const float scale = 63.0f/255.0f;
    float sy = yy*scale, sx = xx*scale;
    int y0 = min((int)floorf(sy), 63), x0 = min((int)floorf(sx), 63);
    int y1 = min(y0+1, 63), x1 = min(x0+1, 63);
    float wy = sy - (float)y0, wx = sx - (float)x0;
    const float* pb = prior + (b<<12);
    float v00 = pb[(y0<<6)+x0], v01 = pb[(y0<<6)+x1];
    float v10 = pb[(y1<<6)+x0], v11 = pb[(y1<<6)+x1];
    float r0 = v00*(1.f-wy) + v10*wy;
    float r1 = v01*(1.f-wy) + v11*wy;
    float v  = r0*(1.f-wx) + r1*wx;
    pu[i] = fminf(fmaxf(v, -1.f), 1.f);
}

// ---------------- K0: fold weights (f16): Wch(384x64), biases, -exp(A), Wof(64x128) ----------
__global__ __launch_bounds__(256) void k_comb(const float* __restrict__ W_in, const float* __restrict__ b_in,
        const float* __restrict__ W_delta, const float* __restrict__ b_delta,
        const float* __restrict__ W_B, const float* __restrict__ b_B,
        const float* __restrict__ A_param, const float* __restrict__ W_out,
        _Float16* __restrict__ Wch, float* __restrict__ bcv, float* __restrict__ negA,
        _Float16* __restrict__ Wof){
    int i = blockIdx.x*256 + threadIdx.x;
    if (i < 24576){
        int r = i >> 6, c = i & 63;
        float v;
        if (r < 128) v = W_in[i];
        else if (r < 256){
            int rr = r-128; float s = 0.f;
            for (int k=0;k<128;k++) s = fmaf(W_delta[(rr<<7)+k], W_in[(k<<6)+c], s);
            v = s;
        } else {
            int rr = r-256; float s = 0.f;
            for (int k=0;k<128;k++) s = fmaf(W_B[(rr<<7)+k], W_in[(k<<6)+c], s);
            v = s;
        }
        Wch[i] = (_Float16)v;
    } else if (i < 24960){
        int r = i - 24576; float v;
        if (r < 128) v = b_in[r];
        else if (r < 256){
            int rr=r-128; float s = b_delta[rr];
            for (int k=0;k<128;k++) s = fmaf(W_delta[(rr<<7)+k], b_in[k], s);
            v = s;
        } else {
            int rr=r-256; float s = b_B[rr];
            for (int k=0;k<128;k++) s = fmaf(W_B[(rr<<7)+k], b_in[k], s);
            v = s;
        }
        bcv[r] = v;
    } else if (i < 25088){
        negA[i-24960] = -expf(A_param[i-24960]);
    } else if (i < 33280){
        Wof[i-25088] = (_Float16)W_out[i-25088];   // [o][k] row-major, 64x128
    }
}

// ---------------- K2: MFMA projection v2 ----------------
// Block: 64 px x all 384 M-rows. Operands SWAPPED: A = X (m=pixel), B = W (n=row).
// D: col=lane&15 = channel-in-tile, row=quad*4+r = pixel -> 4 consecutive px per lane -> 8B stores.
// x converted f32->f16 exactly once (A-frags direct from global, no X LDS).
__global__ __launch_bounds__(256, 2) void k_proj_mfma(const float* __restrict__ x, const float* __restrict__ pu,
        const _Float16* __restrict__ Wch, const float* __restrict__ bcv, const float* __restrict__ negA,
        const float* __restrict__ lam_p, const float* __restrict__ alp_p,
        _Float16* __restrict__ Ab, _Float16* __restrict__ Uu){
    __shared__ _Float16 Ws[384][72];               // pad 64->72: 2-way max (free)

    const int t    = threadIdx.x;
    const int lane = t & 63;
    const int wave = t >> 6;
    const int col  = lane & 15;
    const int quad = lane >> 4;

    const int blk = blockIdx.x;                    // 0..4095
    const int b   = blk >> 10;
    const int p0  = (blk & 1023) << 6;             // 64-px chunk
    const int pxw = p0 + (wave << 4);              // this wave's 16-px tile

    // ---- stage full Wch (384x64 f16 = 48 KB) into LDS ----
    {
        const float4* wsrc = (const float4*)Wch;   // 3072 x 16B chunks (8 per row)
        #pragma unroll
        for (int i = 0; i < 12; i++){
            int c = t + i*256;
            int row = c >> 3, part = c & 7;
            float4 v = wsrc[c];
            *(float4*)&Ws[row][part<<3] = v;
        }
    }

    // ---- A fragments: X[m=pxw+col][k=quad*8+j], f32 global -> f16 ----
    const float* xb = x + ((size_t)b<<22) + pxw + col;
    half8 aX[2];
    #pragma unroll
    for (int kh = 0; kh < 2; kh++){
        half8 h;
        #pragma unroll
        for (int j = 0; j < 8; j++){
            int k = kh*32 + quad*8 + j;
            h[j] = (_Float16)xb[(size_t)k<<16];
        }
        aX[kh] = h;
    }
    __syncthreads();

    // ---- 24 n-tiles x (2 MFMAs): D[px][row] ----
    floatx4 acc[24];
    #pragma unroll
    for (int nt = 0; nt < 24; nt++){
        half8 b0 = *(const half8*)&Ws[nt*16 + col][quad*8];
        half8 b1 = *(const half8*)&Ws[nt*16 + col][32 + quad*8];
        floatx4 a = (floatx4){0.f,0.f,0.f,0.f};
        a = __builtin_amdgcn_mfma_f32_16x16x32_f16(aX[0], b0, a, 0, 0, 0);
        a = __builtin_amdgcn_mfma_f32_16x16x32_f16(aX[1], b1, a, 0, 0, 0);
        acc[nt] = a;
    }

    // ---- epilogue: lane owns 4 consecutive px (quad*4+r) of channel ct*16+col ----
    const float lamv = lam_p[0], alpv = alp_p[0];
    float4 puv4 = *(const float4*)(pu + (b<<16) + pxw + (quad<<2));
    float lpu[4], apu[4];
    #pragma unroll
    for (int r = 0; r < 4; r++){
        float pv = ((const float*)&puv4)[r];
        lpu[r] = lamv * pv;
        apu[r] = fmaf(alpv, pv, 1.f);
    }
    #pragma unroll
    for (int ct = 0; ct < 8; ct++){
        int c = (ct<<4) + col;                     // channel 0..127
        float bI = bcv[c], bD = bcv[128+c], bB = bcv[256+c], nA = negA[c];
        floatx4 aI = acc[ct], aD = acc[8+ct], aB = acc[16+ct];
        h4s oa, ou;
        #pragma unroll
        for (int r = 0; r < 4; r++){
            float sI = aI[r] + bI;
            float sD = aD[r] + bD;
            float sB = aB[r] + bB;
            float dpre  = sD + lpu[r];
            float delta = fmaxf(dpre, 0.f) + __logf(1.f + __expf(-fabsf(dpre)));
            float ab    = __expf(nA * delta);
            float uu    = delta * sB * apu[r] * sI;
            (&oa.x)[r] = (_Float16)ab;
            (&ou.x)[r] = (_Float16)uu;
        }
        size_t o = ((size_t)((b<<7) + c)<<16) + pxw + (quad<<2);
        *(h4s*)(Ab+o) = oa;
        *(h4s*)(Uu+o) = ou;
    }
}

// ---------------- K3: scan along W — one wave per row, shuffle linear-recurrence scan ----------
__global__ __launch_bounds__(256) void k_scan_w(const _Float16* __restrict__ Ab, const _Float16* __restrict__ Uu,
                                                _Float16* __restrict__ Sw){
    int r    = (blockIdx.x<<2) + (threadIdx.x>>6);   // row id over (b,c,h): 0..131071
    int lane = threadIdx.x & 63;
    size_t base = ((size_t)r<<8) + (lane<<2);
    h4s a4 = *(const h4s*)(Ab+base);
    h4s u4 = *(const h4s*)(Uu+base);
    float ax=(float)a4.x, ay=(float)a4.y, az=(float)a4.z, aw=(float)a4.w;
    float ux=(float)u4.x, uy=(float)u4.y, uz=(float)u4.z, uw=(float)u4.w;
    float A = ax, U = ux;
    U = fmaf(ay, U, uy); A *= ay;
    U = fmaf(az, U, uz); A *= az;
    U = fmaf(aw, U, uw); A *= aw;
    #pragma unroll
    for (int off=1; off<64; off<<=1){
        float Apv = __shfl_up(A, off, 64);
        float Upv = __shfl_up(U, off, 64);
        if (lane >= off){ U = fmaf(A, Upv, U); A *= Apv; }
    }
    float h = __shfl_up(U, 1, 64);     // exclusive prefix
    if (lane == 0) h = 0.f;
    float4 o;
    h = fmaf(ax, h, ux); o.x = h;
    h = fmaf(ay, h, uy); o.y = h;
    h = fmaf(az, h, uz); o.z = h;
    h = fmaf(aw, h, uw); o.w = h;
    store4h(Sw+base, o);
}

// ---------------- K4: scan along H (thread per column) + add scanW -> Sh f16 ----------
__global__ __launch_bounds__(256) void k_scan_h(const _Float16* __restrict__ AbH, const _Float16* __restrict__ UuH,
                                                const _Float16* __restrict__ Sw, _Float16* __restrict__ Sh){
    int t   = blockIdx.x*256 + threadIdx.x;    // 0..131071
    int col = t >> 8;                          // b*128 + c
    int w   = t & 255;
    size_t base = ((size_t)col<<16) + w;
    float h = 0.f;
    #pragma unroll 4
    for (int hh=0; hh<256; hh++){
        size_t idx = base + ((size_t)hh<<8);
        float a = (float)AbH[idx];
        float u = (float)UuH[idx];
        float s = (float)Sw[idx];
        h = fmaf(a, h, u);
        Sh[idx] = (_Float16)(h + s);           // scanned = scanH + scanW
    }
}

// ---------------- K5: MFMA output conv (128->64) + residual ----------------
// A = Wof[64][128] f16; B = Sh[k=128][n=px] f16; D: col=pixel, quad*4+r = out-ch within tile.
__global__ __launch_bounds__(256, 2) void k_out_mfma(const float* __restrict__ x, const _Float16* __restrict__ Sh,
        const _Float16* __restrict__ Wof, const float* __restrict__ bout, const float* __restrict__ gam_p,
        float* __restrict__ out){
    const int t    = threadIdx.x;
    const int lane = t & 63;
    const int wave = t >> 6;
    const int col  = lane & 15;
    const int quad = lane >> 4;
    const int b    = blockIdx.x >> 8;
    const int p0   = (blockIdx.x & 255) << 8;
    const int wn0  = wave << 6;

    const _Float16* shb = Sh + ((size_t)b<<23) + p0;

    floatx4 acc[4][4];
    #pragma unroll
    for (int mt = 0; mt < 4; mt++)
        #pragma unroll
        for (int nt = 0; nt < 4; nt++)
            acc[mt][nt] = (floatx4){0.f,0.f,0.f,0.f};

    #pragma unroll
    for (int kc = 0; kc < 4; kc++){
        half8 bf[4];
        #pragma unroll
        for (int nt = 0; nt < 4; nt++){
            int px = wn0 + nt*16 + col;
            #pragma unroll
            for (int j = 0; j < 8; j++)
                bf[nt][j] = shb[((size_t)(kc*32 + quad*8 + j)<<16) + px];
        }
        half8 af[4];
        #pragma unroll
        for (int mt = 0; mt < 4; mt++)
            af[mt] = *(const half8*)(Wof + (mt*16 + col)*128 + kc*32 + quad*8);
        #pragma unroll
        for (int mt = 0; mt < 4; mt++)
            #pragma unroll
            for (int nt = 0; nt < 4; nt++)
                acc[mt][nt] = __builtin_amdgcn_mfma_f32_16x16x32_f16(af[mt], bf[nt], acc[mt][nt], 0, 0, 0);
    }

    const float gv = gam_p[0];
    #pragma unroll
    for (int mt = 0; mt < 4; mt++){
        #pragma unroll
        for (int nt = 0; nt < 4; nt++){
            int px = wn0 + nt*16 + col;
            #pragma unroll
            for (int r = 0; r < 4; r++){
                int o = mt*16 + quad*4 + r;
                size_t idx = (((size_t)(b*64 + o))<<16) + p0 + px;
                out[idx] = fmaf(gv, acc[mt][nt][r] + bout[o], x[idx]);
            }
        }
    }
}

extern "C" void kernel_launch(void* const* d_in, const int* in_sizes, int n_in,
                              void* d_out, int out_size, void* d_ws, size_t ws_size,
                              hipStream_t stream){
    const float* x       = (const float*)d_in[0];
    const float* prior   = (const float*)d_in[1];
    const float* W_in    = (const float*)d_in[2];
    const float* b_in    = (const float*)d_in[3];
    const float* W_out   = (const float*)d_in[4];
    const float* b_out   = (const float*)d_in[5];
    const float* W_delta = (const float*)d_in[6];
    const float* b_delta = (const float*)d_in[7];
    const float* W_B     = (const float*)d_in[8];
    const float* b_B     = (const float*)d_in[9];
    const float* A_param = (const float*)d_in[10];
    const float* lam     = (const float*)d_in[11];
    const float* alp     = (const float*)d_in[12];
    const float* gam     = (const float*)d_in[13];

    float* out = (float*)d_out;
    float* pu  = out + OUT1;                   // prior_up = output 1

    float* ws        = (float*)d_ws;
    _Float16* Wch    = (_Float16*)ws;          // 24576 f16 -> float-offset [0,12288)
    float* bcv       = ws + 12288;             // 384
    float* negA      = ws + 12672;             // 128
    _Float16* Wof    = (_Float16*)(ws + 12800);// 8192 f16 -> [12800,16896)
    _Float16* AbH    = (_Float16*)(ws + 32768);// BIG f16
    _Float16* UuH    = AbH + BIG;              // BIG f16
    _Float16* Sh     = UuH + BIG;              // BIG f16   (total 201.5 MB)
    _Float16* Sw     = (_Float16*)out;         // f16 W-scan scratch in d_out[0:OUT1), 67 MB

    hipLaunchKernelGGL(k_prior,  dim3(1024),  dim3(256), 0, stream, prior, pu);
    hipLaunchKernelGGL(k_comb,   dim3(130),   dim3(256), 0, stream, W_in, b_in, W_delta, b_delta,
                       W_B, b_B, A_param, W_out, Wch, bcv, negA, Wof);
    hipLaunchKernelGGL(k_proj_mfma, dim3(4096), dim3(256), 0, stream,
                       x, pu, Wch, bcv, negA, lam, alp, AbH, UuH);
    hipLaunchKernelGGL(k_scan_w, dim3(32768), dim3(256), 0, stream, AbH, UuH, Sw);
    hipLaunchKernelGGL(k_scan_h, dim3(512),   dim3(256), 0, stream, AbH, UuH, Sw, Sh);
    hipLaunchKernelGGL(k_out_mfma, dim3(1024), dim3(256), 0, stream, x, Sh, Wof, b_out, gam, out);
}